// Round 15
// baseline (215.156 us; speedup 1.0000x reference)
//
#include <hip/hip_runtime.h>
#include <hip/hip_bf16.h>
#include <math.h>

#define NN 100000
#define FF 256
#define EE 128
#define BB_ 10000
#define DD 32

typedef __attribute__((ext_vector_type(8))) short short8;
typedef __attribute__((ext_vector_type(4))) float f32x4;

__device__ __forceinline__ short f2bf(float f) {
  __hip_bfloat16 h = __float2bfloat16(f);   // HW RNE cvt
  union { __hip_bfloat16 h; short s; } u; u.h = h;
  return u.s;
}
__device__ __forceinline__ float bf2f(short s) {
  union { unsigned u; float f; } v;
  v.u = ((unsigned)(unsigned short)s) << 16;
  return v.f;
}

// async global->LDS, 16B per lane; LDS dest = wave-uniform base + lane*16
__device__ __forceinline__ void gll16(const float* g, float* lds) {
  __builtin_amdgcn_global_load_lds(
      (const __attribute__((address_space(1))) unsigned int*)g,
      (__attribute__((address_space(3))) unsigned int*)lds, 16, 0, 0);
}

// ---- prep: Wef32 = W*z (fp32), BT2 X-rows, a1wTc, w2T, bias2[0:128] ----
__global__ __launch_bounds__(256) void k_prep(
    const float* __restrict__ W, const float* __restrict__ qz,
    const float* __restrict__ a1w, const float* __restrict__ a2w,
    const float* __restrict__ bb,
    float* __restrict__ Wef32, short* __restrict__ BT2,
    short* __restrict__ a1wTc, short* __restrict__ w2T,
    float* __restrict__ bias2) {
  int i = blockIdx.x * 256 + threadIdx.x;
  if (i < 32768) {                       // (f,e): We = W*z
    int f = i >> 7, e = i & 127;
    float g = qz[f];
    float s = 1.0f / (1.0f + expf(-g));
    float z = fminf(fmaxf(s * 1.2f - 0.1f, 0.0f), 1.0f);
    float v = W[f * 128 + e] * z;
    Wef32[f * 128 + e] = v;
    BT2[e * 256 + f] = f2bf(v);          // X-part rows of combined BT
  } else if (i < 49152) {                // a1wTc[n][k] = a1w[128+k][n]
    int t = i - 32768; int n = t >> 7, k = t & 127;
    a1wTc[n * 128 + k] = f2bf(a1w[(128 + k) * 128 + n]);
  } else if (i < 65536) {                // w2T[n][k] = a2w[k][n]
    int t = i - 49152; int n = t >> 7, k = t & 127;
    w2T[n * 128 + k] = f2bf(a2w[k * 128 + n]);
  } else if (i < 65664) {                // bias2[0:128] = b
    bias2[i - 65536] = bb[i - 65536];
  }
}

// ---- compose: BT2 Y-rows = (We @ A1n)^T, bias2[128:] = b@A1n + a1b ----
__global__ __launch_bounds__(256) void k_compose(
    const float* __restrict__ Wef32, const float* __restrict__ a1w,
    const float* __restrict__ a1b, const float* __restrict__ bb,
    short* __restrict__ BT2, float* __restrict__ bias2) {
  const int n = blockIdx.x;       // 0..127 output col of Y
  const int f = threadIdx.x;      // 0..255
  float s = 0.f;
  for (int e = 0; e < 128; ++e)
    s = fmaf(a1w[e * 128 + n], Wef32[f * 128 + e], s);
  BT2[(size_t)(128 + n) * 256 + f] = f2bf(s);
  if (f == 0) {
    float by = a1b[n];
    for (int e = 0; e < 128; ++e) by = fmaf(bb[e], a1w[e * 128 + n], by);
    bias2[128 + n] = by;
  }
}

// ---- XY GEMM v6: persistent blocks, double-buffered gll staging, counted
// vmcnt.  XY[M][256] = feature[M][256] @ BT2[256][256]^T + bias2
__global__ __launch_bounds__(256) void k_xy(
    const float* __restrict__ feat, const short* __restrict__ BT2,
    const float* __restrict__ bias2, short* __restrict__ XY, int M) {
  __shared__ float As[2][32 * 256];   // 2 x 32 KiB fp32
  const int tid = threadIdx.x;
  const int wave = tid >> 6, lane = tid & 63;
  const int wn = wave;                        // col block
  const int l15 = lane & 15, lg = lane >> 4;
  const int NT = M >> 5;                      // 3125 (M % 32 == 0)
  const int G = gridDim.x;

  // ---- B fragments + bias: hoisted, one L2 round-trip
  short8 bfr[8][4];
#pragma unroll
  for (int ks = 0; ks < 8; ++ks)
#pragma unroll
    for (int j = 0; j < 4; ++j)
      bfr[ks][j] = *(const short8*)(BT2 +
          (size_t)(wn * 64 + j * 16 + l15) * 256 + (ks * 4 + lg) * 8);
  float bv4[4];
#pragma unroll
  for (int j = 0; j < 4; ++j) bv4[j] = bias2[wn * 64 + j * 16 + l15];

  int t = blockIdx.x;
  if (t < NT) {                               // prologue: stage tile t -> buf0
#pragma unroll
    for (int it = 0; it < 8; ++it) {
      int r = it * 4 + wave;
      gll16(feat + (size_t)(t * 32 + r) * 256 + ((lane ^ (r & 7)) * 4),
            &As[0][r * 256]);
    }
  }

  int cur = 0;
  for (; t < NT; t += G) {
    const int tn = t + G;
    __builtin_amdgcn_s_barrier();             // b1: buf (cur^1) free to fill
    if (tn < NT) {
#pragma unroll
      for (int it = 0; it < 8; ++it) {
        int r = it * 4 + wave;
        gll16(feat + (size_t)(tn * 32 + r) * 256 + ((lane ^ (r & 7)) * 4),
              &As[cur ^ 1][r * 256]);
      }
      asm volatile("s_waitcnt vmcnt(8)" ::: "memory");  // cur landed; 8 fly on
    } else {
      asm volatile("s_waitcnt vmcnt(0)" ::: "memory");  // tail: drain all
    }
    __builtin_amdgcn_s_barrier();             // b2: cur visible to all waves
    __builtin_amdgcn_sched_barrier(0);

    f32x4 acc[2][4];
#pragma unroll
    for (int i = 0; i < 2; ++i)
#pragma unroll
      for (int j = 0; j < 4; ++j) acc[i][j] = (f32x4){0.f, 0.f, 0.f, 0.f};

    const float* Ab = &As[cur][0];
#pragma unroll
    for (int ks = 0; ks < 8; ++ks) {
      const int kg = ks * 4 + lg;             // 8-float k-group
#pragma unroll
      for (int i = 0; i < 2; ++i) {
        const int r = i * 16 + l15;
        const int sw = r & 7;
        const int c0 = (2 * kg) ^ sw;
        const int c1 = (2 * kg + 1) ^ sw;
        float4 flo = *(const float4*)(Ab + r * 256 + c0 * 4);
        float4 fhi = *(const float4*)(Ab + r * 256 + c1 * 4);
        short8 af;
        af[0] = f2bf(flo.x); af[1] = f2bf(flo.y);
        af[2] = f2bf(flo.z); af[3] = f2bf(flo.w);
        af[4] = f2bf(fhi.x); af[5] = f2bf(fhi.y);
        af[6] = f2bf(fhi.z); af[7] = f2bf(fhi.w);
        __builtin_amdgcn_s_setprio(1);
#pragma unroll
        for (int j = 0; j < 4; ++j)
          acc[i][j] = __builtin_amdgcn_mfma_f32_16x16x32_bf16(
              af, bfr[ks][j], acc[i][j], 0, 0, 0);
        __builtin_amdgcn_s_setprio(0);
      }
    }

#pragma unroll
    for (int i = 0; i < 2; ++i) {
#pragma unroll
      for (int r = 0; r < 4; ++r) {
        int row = t * 32 + i * 16 + lg * 4 + r;
#pragma unroll
        for (int j = 0; j < 4; ++j) {
          int col = wn * 64 + j * 16 + l15;
          XY[(size_t)row * 256 + col] = f2bf(acc[i][j][r] + bv4[j]);
        }
      }
    }
    cur ^= 1;
  }
}

// ---- MFMA GEMM (used for P): C = A(rows via idx, stride LDA)@BT^T + bias --
template <int K, int LDA, int LDC, bool AF32, bool OUTBF16>
__global__ __launch_bounds__(256) void k_mm(
    const void* __restrict__ Ap, const short* __restrict__ BT,
    const float* __restrict__ bias, const int* __restrict__ idx,
    void* __restrict__ Cp, int M) {
  __shared__ short As[128 * 64];
  __shared__ short Bs[128 * 64];
  const int tid = threadIdx.x;
  const int mb = blockIdx.x * 128;
  const int col0 = blockIdx.y * 128;
  const int wave = tid >> 6, lane = tid & 63;
  const int wr = wave >> 1, wc = wave & 1;
  const int l15 = lane & 15, lg = lane >> 4;

  size_t abase[4];
#pragma unroll
  for (int s = 0; s < 4; ++s) {
    int row = (tid + s * 256) >> 3;
    int grow = mb + row;
    int gr = 0;
    if (grow < M) gr = idx ? idx[grow] : grow;
    abase[s] = (size_t)gr * LDA;
  }

  f32x4 acc[4][4];
#pragma unroll
  for (int i = 0; i < 4; ++i)
#pragma unroll
    for (int j = 0; j < 4; ++j) acc[i][j] = (f32x4){0.f, 0.f, 0.f, 0.f};

  for (int k0 = 0; k0 < K; k0 += 64) {
#pragma unroll
    for (int s = 0; s < 4; ++s) {
      int q = tid + s * 256;
      int row = q >> 3, c = q & 7;
      short8 av;
      if (AF32) {
        const float* ap = (const float*)Ap + abase[s] + k0 + c * 8;
        float4 f0 = *(const float4*)ap;
        float4 f1 = *(const float4*)(ap + 4);
        av[0] = f2bf(f0.x); av[1] = f2bf(f0.y);
        av[2] = f2bf(f0.z); av[3] = f2bf(f0.w);
        av[4] = f2bf(f1.x); av[5] = f2bf(f1.y);
        av[6] = f2bf(f1.z); av[7] = f2bf(f1.w);
      } else {
        av = *(const short8*)((const short*)Ap + abase[s] + k0 + c * 8);
      }
      *(short8*)(As + row * 64 + 8 * (c ^ (row & 7))) = av;
      short8 bv = *(const short8*)(BT + (size_t)(col0 + row) * K + k0 + c * 8);
      *(short8*)(Bs + row * 64 + 8 * (c ^ (row & 7))) = bv;
    }
    __syncthreads();
#pragma unroll
    for (int ks = 0; ks < 2; ++ks) {
      int c = ks * 4 + lg;
      short8 af[4], bfv[4];
#pragma unroll
      for (int i = 0; i < 4; ++i) {
        int r = wr * 64 + i * 16 + l15;
        af[i] = *(short8*)(As + r * 64 + 8 * (c ^ (r & 7)));
        int n = wc * 64 + i * 16 + l15;
        bfv[i] = *(short8*)(Bs + n * 64 + 8 * (c ^ (n & 7)));
      }
#pragma unroll
      for (int i = 0; i < 4; ++i)
#pragma unroll
        for (int j = 0; j < 4; ++j)
          acc[i][j] = __builtin_amdgcn_mfma_f32_16x16x32_bf16(
              af[i], bfv[j], acc[i][j], 0, 0, 0);
    }
    __syncthreads();
  }

  float bv4[4];
#pragma unroll
  for (int j = 0; j < 4; ++j) {
    int col = wc * 64 + j * 16 + l15;
    bv4[j] = bias ? bias[col0 + col] : 0.f;
  }
#pragma unroll
  for (int i = 0; i < 4; ++i) {
#pragma unroll
    for (int r = 0; r < 4; ++r) {
      int row = mb + wr * 64 + i * 16 + lg * 4 + r;
      if (row < M) {
#pragma unroll
        for (int j = 0; j < 4; ++j) {
          int col = wc * 64 + j * 16 + l15;
          float v = acc[i][j][r] + bv4[j];
          if (OUTBF16)
            ((short*)Cp)[(size_t)row * LDC + col0 + col] = f2bf(v);
          else
            ((float*)Cp)[(size_t)row * LDC + col0 + col] = v;
        }
      }
    }
  }
}

// ---- fused attention v10: attn7 structure (2 centers/wave) with the two
// centers' MFMA blocks SERIALIZED sharing one 32-reg accumulator (was 64
// live) + in-fold b2/w3 loads + sunk fallbacks. Natural VGPR pressure
// ~155-165 fits the waves_per_eu(3) budget (170) WITHOUT spill -> 3
// waves/SIMD x 2 centers = 6 streams/SIMD (was 4). Per-center arithmetic
// order unchanged -> bit-identical output.
__global__ __launch_bounds__(256)
__attribute__((amdgpu_waves_per_eu(3))) void k_attn10(
    const short* __restrict__ XY, const float* __restrict__ P,
    const int* __restrict__ nodes, const int* __restrict__ nidx,
    const int* __restrict__ nmask, const short* __restrict__ w2T,
    const float* __restrict__ b2, const float* __restrict__ w3,
    const float* __restrict__ b3, float* __restrict__ out) {
  __shared__ float sc_s[4][2][32];
  __shared__ float att_s[4][2][32];
  const int tid = threadIdx.x;
  const int wave = tid >> 6, lane = tid & 63;
  const int l15 = lane & 15, lg = lane >> 4;
  const int dl = lane & 31;
  const int b0 = (blockIdx.x * 4 + wave) * 2;
  const int b1 = b0 + 1;
  const float b3v = b3[0];

  // ---- RT1: indices, masks (both centers)
  const int ni0 = nidx[b0 * DD + dl];
  const int ni1 = nidx[b1 * DD + dl];
  const int m0 = nmask[b0 * DD + dl];
  const int m1 = nmask[b1 * DD + dl];

  const int r00 = __shfl(ni0, l15), r01 = __shfl(ni0, 16 + l15);
  const int r10 = __shfl(ni1, l15), r11 = __shfl(ni1, 16 + l15);

  // ---- RT2: Y rows for both centers + P(c0)
  short8 y00[4], y01[4], y10[4], y11[4];
#pragma unroll
  for (int ks = 0; ks < 4; ++ks) {
    const int k0 = ks * 32 + lg * 8;
    y00[ks] = *(const short8*)(XY + (size_t)r00 * 256 + 128 + k0);
    y01[ks] = *(const short8*)(XY + (size_t)r01 * 256 + 128 + k0);
    y10[ks] = *(const short8*)(XY + (size_t)r10 * 256 + 128 + k0);
    y11[ks] = *(const short8*)(XY + (size_t)r11 * 256 + 128 + k0);
  }
  float4 pv[8];
#pragma unroll
  for (int q = 0; q < 4; ++q) {
    const int k0 = q * 32 + lg * 8;
    pv[2 * q] = *(const float4*)(P + (size_t)b0 * EE + k0);
    pv[2 * q + 1] = *(const float4*)(P + (size_t)b0 * EE + k0 + 4);
  }

  // ---- h1(c0) -> fragments (frees y00/y01 and pv)
  short8 f00[4], f01[4];
#pragma unroll
  for (int ks = 0; ks < 4; ++ks) {
    float pf[8] = {pv[2 * ks].x, pv[2 * ks].y, pv[2 * ks].z, pv[2 * ks].w,
                   pv[2 * ks + 1].x, pv[2 * ks + 1].y, pv[2 * ks + 1].z,
                   pv[2 * ks + 1].w};
#pragma unroll
    for (int e = 0; e < 8; ++e) {
      f00[ks][e] = f2bf(fmaxf(bf2f(y00[ks][e]) + pf[e], 0.f));
      f01[ks][e] = f2bf(fmaxf(bf2f(y01[ks][e]) + pf[e], 0.f));
    }
  }

  // ---- issue P(c1) + X gathers (c0)
#pragma unroll
  for (int q = 0; q < 4; ++q) {
    const int k0 = q * 32 + lg * 8;
    pv[2 * q] = *(const float4*)(P + (size_t)b1 * EE + k0);
    pv[2 * q + 1] = *(const float4*)(P + (size_t)b1 * EE + k0 + 4);
  }
  unsigned xv0[32];
#pragma unroll
  for (int d = 0; d < 32; ++d)
    xv0[d] = *(const unsigned*)(XY + (size_t)__shfl(ni0, d) * 256 + 2 * lane);

  // ---- h1(c1) -> fragments
  short8 f10[4], f11[4];
#pragma unroll
  for (int ks = 0; ks < 4; ++ks) {
    float pf[8] = {pv[2 * ks].x, pv[2 * ks].y, pv[2 * ks].z, pv[2 * ks].w,
                   pv[2 * ks + 1].x, pv[2 * ks + 1].y, pv[2 * ks + 1].z,
                   pv[2 * ks + 1].w};
#pragma unroll
    for (int e = 0; e < 8; ++e) {
      f10[ks][e] = f2bf(fmaxf(bf2f(y10[ks][e]) + pf[e], 0.f));
      f11[ks][e] = f2bf(fmaxf(bf2f(y11[ks][e]) + pf[e], 0.f));
    }
  }

  // ---- c0 MFMA (col-split, shared accumulator) ----
  float sp0[2][4], sp1[2][4];
#pragma unroll
  for (int i = 0; i < 2; ++i)
#pragma unroll
    for (int r = 0; r < 4; ++r) { sp0[i][r] = 0.f; sp1[i][r] = 0.f; }

#pragma unroll
  for (int cg = 0; cg < 2; ++cg) {
    f32x4 ac[2][4];
#pragma unroll
    for (int i = 0; i < 2; ++i)
#pragma unroll
      for (int j = 0; j < 4; ++j) ac[i][j] = (f32x4){0.f, 0.f, 0.f, 0.f};
#pragma unroll
    for (int ks = 0; ks < 4; ++ks) {
      const int k0 = ks * 32 + lg * 8;
      short8 bfv[4];
#pragma unroll
      for (int j = 0; j < 4; ++j)
        bfv[j] = *(const short8*)(w2T +
            (size_t)(cg * 64 + j * 16 + l15) * EE + k0);
      __builtin_amdgcn_s_setprio(1);
#pragma unroll
      for (int j = 0; j < 4; ++j) {
        ac[0][j] = __builtin_amdgcn_mfma_f32_16x16x32_bf16(
            f00[ks], bfv[j], ac[0][j], 0, 0, 0);
        ac[1][j] = __builtin_amdgcn_mfma_f32_16x16x32_bf16(
            f01[ks], bfv[j], ac[1][j], 0, 0, 0);
      }
      __builtin_amdgcn_s_setprio(0);
    }
#pragma unroll
    for (int j = 0; j < 4; ++j) {
      const int col = cg * 64 + j * 16 + l15;
      const float b2v = b2[col];
      const float w3v = w3[col];
#pragma unroll
      for (int i = 0; i < 2; ++i)
#pragma unroll
        for (int r = 0; r < 4; ++r)
          sp0[i][r] += fmaxf(ac[i][j][r] + b2v, 0.f) * w3v;
    }
  }

  // ---- issue X gathers (c1) — hide under c1's MFMA block
  unsigned xv1[32];
#pragma unroll
  for (int d = 0; d < 32; ++d)
    xv1[d] = *(const unsigned*)(XY + (size_t)__shfl(ni1, d) * 256 + 2 * lane);

  // ---- c1 MFMA (col-split, accumulator reused) ----
#pragma unroll
  for (int cg = 0; cg < 2; ++cg) {
    f32x4 ac[2][4];
#pragma unroll
    for (int i = 0; i < 2; ++i)
#pragma unroll
      for (int j = 0; j < 4; ++j) ac[i][j] = (f32x4){0.f, 0.f, 0.f, 0.f};
#pragma unroll
    for (int ks = 0; ks < 4; ++ks) {
      const int k0 = ks * 32 + lg * 8;
      short8 bfv[4];
#pragma unroll
      for (int j = 0; j < 4; ++j)
        bfv[j] = *(const short8*)(w2T +
            (size_t)(cg * 64 + j * 16 + l15) * EE + k0);
      __builtin_amdgcn_s_setprio(1);
#pragma unroll
      for (int j = 0; j < 4; ++j) {
        ac[0][j] = __builtin_amdgcn_mfma_f32_16x16x32_bf16(
            f10[ks], bfv[j], ac[0][j], 0, 0, 0);
        ac[1][j] = __builtin_amdgcn_mfma_f32_16x16x32_bf16(
            f11[ks], bfv[j], ac[1][j], 0, 0, 0);
      }
      __builtin_amdgcn_s_setprio(0);
    }
#pragma unroll
    for (int j = 0; j < 4; ++j) {
      const int col = cg * 64 + j * 16 + l15;
      const float b2v = b2[col];
      const float w3v = w3[col];
#pragma unroll
      for (int i = 0; i < 2; ++i)
#pragma unroll
        for (int r = 0; r < 4; ++r)
          sp1[i][r] += fmaxf(ac[i][j][r] + b2v, 0.f) * w3v;
    }
  }

  // ---- reduce score partials across the 16-lane col group
#pragma unroll
  for (int off = 1; off <= 8; off <<= 1) {
#pragma unroll
    for (int i = 0; i < 2; ++i)
#pragma unroll
      for (int r = 0; r < 4; ++r) {
        sp0[i][r] += __shfl_xor(sp0[i][r], off);
        sp1[i][r] += __shfl_xor(sp1[i][r], off);
      }
  }
  if (l15 == 0) {
#pragma unroll
    for (int i = 0; i < 2; ++i)
#pragma unroll
      for (int r = 0; r < 4; ++r) {
        sc_s[wave][0][i * 16 + lg * 4 + r] = sp0[i][r];
        sc_s[wave][1][i * 16 + lg * 4 + r] = sp1[i][r];
      }
  }

  // ---- dual softmax: lanes 0-31 handle c0, lanes 32-63 handle c1
  const int half = lane >> 5;
  const int row = dl;
  const int mh = half ? m1 : m0;
  float s = sc_s[wave][half][row] + b3v;
  if (!mh) s = -1e30f;
  float mx = s;
#pragma unroll
  for (int off = 1; off <= 16; off <<= 1) mx = fmaxf(mx, __shfl_xor(mx, off));
  float e = expf(s - mx);
  float sum = e;
#pragma unroll
  for (int off = 1; off <= 16; off <<= 1) sum += __shfl_xor(sum, off);
  att_s[wave][half][row] = e / sum;
  const unsigned long long bal = __ballot(mh != 0);
  const bool has0 = (bal & 0xffffffffull) != 0ull;
  const bool has1 = (bal >> 32) != 0ull;

  // ---- agg both centers on prefetched X; fallback loads sunk
  float a00 = 0.f, a01 = 0.f;
  if (has0) {
#pragma unroll
    for (int d = 0; d < 32; ++d) {
      const float a = att_s[wave][0][d];
      a00 += a * bf2f((short)(xv0[d] & 0xffffu));
      a01 += a * bf2f((short)(xv0[d] >> 16));
    }
  } else {
    const unsigned xfb0 =
        *(const unsigned*)(XY + (size_t)nodes[b0] * 256 + 2 * lane);
    a00 = bf2f((short)(xfb0 & 0xffffu));
    a01 = bf2f((short)(xfb0 >> 16));
  }
  *(float2*)(out + (size_t)b0 * EE + 2 * lane) = make_float2(a00, a01);

  float a10 = 0.f, a11 = 0.f;
  if (has1) {
#pragma unroll
    for (int d = 0; d < 32; ++d) {
      const float a = att_s[wave][1][d];
      a10 += a * bf2f((short)(xv1[d] & 0xffffu));
      a11 += a * bf2f((short)(xv1[d] >> 16));
    }
  } else {
    const unsigned xfb1 =
        *(const unsigned*)(XY + (size_t)nodes[b1] * 256 + 2 * lane);
    a10 = bf2f((short)(xfb1 & 0xffffu));
    a11 = bf2f((short)(xfb1 >> 16));
  }
  *(float2*)(out + (size_t)b1 * EE + 2 * lane) = make_float2(a10, a11);
}

extern "C" void kernel_launch(void* const* d_in, const int* in_sizes, int n_in,
                              void* d_out, int out_size, void* d_ws,
                              size_t ws_size, hipStream_t stream) {
  const int* nodes = (const int*)d_in[0];
  const int* nidx = (const int*)d_in[1];
  const int* nmask = (const int*)d_in[2];
  const float* feature = (const float*)d_in[3];
  const float* W = (const float*)d_in[4];
  const float* bb = (const float*)d_in[5];
  const float* qz = (const float*)d_in[6];
  const float* a1w = (const float*)d_in[7];
  const float* a1b = (const float*)d_in[8];
  const float* a2w = (const float*)d_in[9];
  const float* a2b = (const float*)d_in[10];
  const float* a3w = (const float*)d_in[11];
  const float* a3b = (const float*)d_in[12];
  float* out = (float*)d_out;

  char* ws = (char*)d_ws;
  short* BT2   = (short*)(ws);                       // 128 KiB [256][256] bf16
  float* Wef32 = (float*)(ws + 131072);              // 128 KiB
  short* a1wTc = (short*)(ws + 262144);              // 32 KiB
  short* w2T   = (short*)(ws + 294912);              // 32 KiB
  float* bias2 = (float*)(ws + 327680);              // 1 KiB
  short* XYb   = (short*)(ws + 524288);              // 51.2 MB bf16 [N][256]
  float* Pv    = (float*)(ws + 524288 + 51200000);   // 5.12 MB fp32

  k_prep<<<257, 256, 0, stream>>>(W, qz, a1w, a2w, bb, Wef32, BT2, a1wTc, w2T,
                                  bias2);
  k_compose<<<128, 256, 0, stream>>>(Wef32, a1w, a1b, bb, BT2, bias2);
  // XY = feature @ [We|Wy] + bias2    [100000,256]x[256,256] -> bf16
  k_xy<<<512, 256, 0, stream>>>(feature, BT2, bias2, XYb, NN);
  // P = X[nodes] @ att1_w[128:]       [10000,128]x[128,128] -> fp32
  k_mm<128, 256, 128, false, false><<<dim3((BB_ + 127) / 128, 1), 256, 0,
                                      stream>>>(XYb, a1wTc, nullptr, nodes, Pv,
                                                BB_);
  // fused attention: 2 centers/wave, serialized MFMA blocks, 3 waves/SIMD
  k_attn10<<<BB_ / 8, 256, 0, stream>>>(XYb, Pv, nodes, nidx, nmask, w2T, a2b,
                                        a3w, a3b, out);
}

// Round 16
// 145.469 us; speedup vs baseline: 1.4791x; 1.4791x over previous
//
#include <hip/hip_runtime.h>
#include <hip/hip_bf16.h>
#include <math.h>

#define NN 100000
#define FF 256
#define EE 128
#define BB_ 10000
#define DD 32

typedef __attribute__((ext_vector_type(8))) short short8;
typedef __attribute__((ext_vector_type(4))) float f32x4;

__device__ __forceinline__ short f2bf(float f) {
  __hip_bfloat16 h = __float2bfloat16(f);   // HW RNE cvt
  union { __hip_bfloat16 h; short s; } u; u.h = h;
  return u.s;
}
__device__ __forceinline__ float bf2f(short s) {
  union { unsigned u; float f; } v;
  v.u = ((unsigned)(unsigned short)s) << 16;
  return v.f;
}

// async global->LDS, 16B per lane; LDS dest = wave-uniform base + lane*16
__device__ __forceinline__ void gll16(const float* g, float* lds) {
  __builtin_amdgcn_global_load_lds(
      (const __attribute__((address_space(1))) unsigned int*)g,
      (__attribute__((address_space(3))) unsigned int*)lds, 16, 0, 0);
}

// ---- prep: Wef32 = W*z (fp32), BT2 X-rows, a1wTc, w2T, bias2[0:128] ----
__global__ __launch_bounds__(256) void k_prep(
    const float* __restrict__ W, const float* __restrict__ qz,
    const float* __restrict__ a1w, const float* __restrict__ a2w,
    const float* __restrict__ bb,
    float* __restrict__ Wef32, short* __restrict__ BT2,
    short* __restrict__ a1wTc, short* __restrict__ w2T,
    float* __restrict__ bias2) {
  int i = blockIdx.x * 256 + threadIdx.x;
  if (i < 32768) {                       // (f,e): We = W*z
    int f = i >> 7, e = i & 127;
    float g = qz[f];
    float s = 1.0f / (1.0f + expf(-g));
    float z = fminf(fmaxf(s * 1.2f - 0.1f, 0.0f), 1.0f);
    float v = W[f * 128 + e] * z;
    Wef32[f * 128 + e] = v;
    BT2[e * 256 + f] = f2bf(v);          // X-part rows of combined BT
  } else if (i < 49152) {                // a1wTc[n][k] = a1w[128+k][n]
    int t = i - 32768; int n = t >> 7, k = t & 127;
    a1wTc[n * 128 + k] = f2bf(a1w[(128 + k) * 128 + n]);
  } else if (i < 65536) {                // w2T[n][k] = a2w[k][n]
    int t = i - 49152; int n = t >> 7, k = t & 127;
    w2T[n * 128 + k] = f2bf(a2w[k * 128 + n]);
  } else if (i < 65664) {                // bias2[0:128] = b
    bias2[i - 65536] = bb[i - 65536];
  }
}

// ---- compose: BT2 Y-rows = (We @ A1n)^T, bias2[128:] = b@A1n + a1b ----
__global__ __launch_bounds__(256) void k_compose(
    const float* __restrict__ Wef32, const float* __restrict__ a1w,
    const float* __restrict__ a1b, const float* __restrict__ bb,
    short* __restrict__ BT2, float* __restrict__ bias2) {
  const int n = blockIdx.x;       // 0..127 output col of Y
  const int f = threadIdx.x;      // 0..255
  float s = 0.f;
  for (int e = 0; e < 128; ++e)
    s = fmaf(a1w[e * 128 + n], Wef32[f * 128 + e], s);
  BT2[(size_t)(128 + n) * 256 + f] = f2bf(s);
  if (f == 0) {
    float by = a1b[n];
    for (int e = 0; e < 128; ++e) by = fmaf(bb[e], a1w[e * 128 + n], by);
    bias2[128 + n] = by;
  }
}

// ---- XY GEMM v6: persistent blocks, double-buffered gll staging, counted
// vmcnt.  XY[M][256] = feature[M][256] @ BT2[256][256]^T + bias2
__global__ __launch_bounds__(256) void k_xy(
    const float* __restrict__ feat, const short* __restrict__ BT2,
    const float* __restrict__ bias2, short* __restrict__ XY, int M) {
  __shared__ float As[2][32 * 256];   // 2 x 32 KiB fp32
  const int tid = threadIdx.x;
  const int wave = tid >> 6, lane = tid & 63;
  const int wn = wave;                        // col block
  const int l15 = lane & 15, lg = lane >> 4;
  const int NT = M >> 5;                      // 3125 (M % 32 == 0)
  const int G = gridDim.x;

  // ---- B fragments + bias: hoisted, one L2 round-trip
  short8 bfr[8][4];
#pragma unroll
  for (int ks = 0; ks < 8; ++ks)
#pragma unroll
    for (int j = 0; j < 4; ++j)
      bfr[ks][j] = *(const short8*)(BT2 +
          (size_t)(wn * 64 + j * 16 + l15) * 256 + (ks * 4 + lg) * 8);
  float bv4[4];
#pragma unroll
  for (int j = 0; j < 4; ++j) bv4[j] = bias2[wn * 64 + j * 16 + l15];

  int t = blockIdx.x;
  if (t < NT) {                               // prologue: stage tile t -> buf0
#pragma unroll
    for (int it = 0; it < 8; ++it) {
      int r = it * 4 + wave;
      gll16(feat + (size_t)(t * 32 + r) * 256 + ((lane ^ (r & 7)) * 4),
            &As[0][r * 256]);
    }
  }

  int cur = 0;
  for (; t < NT; t += G) {
    const int tn = t + G;
    __builtin_amdgcn_s_barrier();             // b1: buf (cur^1) free to fill
    if (tn < NT) {
#pragma unroll
      for (int it = 0; it < 8; ++it) {
        int r = it * 4 + wave;
        gll16(feat + (size_t)(tn * 32 + r) * 256 + ((lane ^ (r & 7)) * 4),
              &As[cur ^ 1][r * 256]);
      }
      asm volatile("s_waitcnt vmcnt(8)" ::: "memory");  // cur landed; 8 fly on
    } else {
      asm volatile("s_waitcnt vmcnt(0)" ::: "memory");  // tail: drain all
    }
    __builtin_amdgcn_s_barrier();             // b2: cur visible to all waves
    __builtin_amdgcn_sched_barrier(0);

    f32x4 acc[2][4];
#pragma unroll
    for (int i = 0; i < 2; ++i)
#pragma unroll
      for (int j = 0; j < 4; ++j) acc[i][j] = (f32x4){0.f, 0.f, 0.f, 0.f};

    const float* Ab = &As[cur][0];
#pragma unroll
    for (int ks = 0; ks < 8; ++ks) {
      const int kg = ks * 4 + lg;             // 8-float k-group
#pragma unroll
      for (int i = 0; i < 2; ++i) {
        const int r = i * 16 + l15;
        const int sw = r & 7;
        const int c0 = (2 * kg) ^ sw;
        const int c1 = (2 * kg + 1) ^ sw;
        float4 flo = *(const float4*)(Ab + r * 256 + c0 * 4);
        float4 fhi = *(const float4*)(Ab + r * 256 + c1 * 4);
        short8 af;
        af[0] = f2bf(flo.x); af[1] = f2bf(flo.y);
        af[2] = f2bf(flo.z); af[3] = f2bf(flo.w);
        af[4] = f2bf(fhi.x); af[5] = f2bf(fhi.y);
        af[6] = f2bf(fhi.z); af[7] = f2bf(fhi.w);
        __builtin_amdgcn_s_setprio(1);
#pragma unroll
        for (int j = 0; j < 4; ++j)
          acc[i][j] = __builtin_amdgcn_mfma_f32_16x16x32_bf16(
              af, bfr[ks][j], acc[i][j], 0, 0, 0);
        __builtin_amdgcn_s_setprio(0);
      }
    }

#pragma unroll
    for (int i = 0; i < 2; ++i) {
#pragma unroll
      for (int r = 0; r < 4; ++r) {
        int row = t * 32 + i * 16 + lg * 4 + r;
#pragma unroll
        for (int j = 0; j < 4; ++j) {
          int col = wn * 64 + j * 16 + l15;
          XY[(size_t)row * 256 + col] = f2bf(acc[i][j][r] + bv4[j]);
        }
      }
    }
    cur ^= 1;
  }
}

// ---- MFMA GEMM (used for P): C = A(rows via idx, stride LDA)@BT^T + bias --
template <int K, int LDA, int LDC, bool AF32, bool OUTBF16>
__global__ __launch_bounds__(256) void k_mm(
    const void* __restrict__ Ap, const short* __restrict__ BT,
    const float* __restrict__ bias, const int* __restrict__ idx,
    void* __restrict__ Cp, int M) {
  __shared__ short As[128 * 64];
  __shared__ short Bs[128 * 64];
  const int tid = threadIdx.x;
  const int mb = blockIdx.x * 128;
  const int col0 = blockIdx.y * 128;
  const int wave = tid >> 6, lane = tid & 63;
  const int wr = wave >> 1, wc = wave & 1;
  const int l15 = lane & 15, lg = lane >> 4;

  size_t abase[4];
#pragma unroll
  for (int s = 0; s < 4; ++s) {
    int row = (tid + s * 256) >> 3;
    int grow = mb + row;
    int gr = 0;
    if (grow < M) gr = idx ? idx[grow] : grow;
    abase[s] = (size_t)gr * LDA;
  }

  f32x4 acc[4][4];
#pragma unroll
  for (int i = 0; i < 4; ++i)
#pragma unroll
    for (int j = 0; j < 4; ++j) acc[i][j] = (f32x4){0.f, 0.f, 0.f, 0.f};

  for (int k0 = 0; k0 < K; k0 += 64) {
#pragma unroll
    for (int s = 0; s < 4; ++s) {
      int q = tid + s * 256;
      int row = q >> 3, c = q & 7;
      short8 av;
      if (AF32) {
        const float* ap = (const float*)Ap + abase[s] + k0 + c * 8;
        float4 f0 = *(const float4*)ap;
        float4 f1 = *(const float4*)(ap + 4);
        av[0] = f2bf(f0.x); av[1] = f2bf(f0.y);
        av[2] = f2bf(f0.z); av[3] = f2bf(f0.w);
        av[4] = f2bf(f1.x); av[5] = f2bf(f1.y);
        av[6] = f2bf(f1.z); av[7] = f2bf(f1.w);
      } else {
        av = *(const short8*)((const short*)Ap + abase[s] + k0 + c * 8);
      }
      *(short8*)(As + row * 64 + 8 * (c ^ (row & 7))) = av;
      short8 bv = *(const short8*)(BT + (size_t)(col0 + row) * K + k0 + c * 8);
      *(short8*)(Bs + row * 64 + 8 * (c ^ (row & 7))) = bv;
    }
    __syncthreads();
#pragma unroll
    for (int ks = 0; ks < 2; ++ks) {
      int c = ks * 4 + lg;
      short8 af[4], bfv[4];
#pragma unroll
      for (int i = 0; i < 4; ++i) {
        int r = wr * 64 + i * 16 + l15;
        af[i] = *(short8*)(As + r * 64 + 8 * (c ^ (r & 7)));
        int n = wc * 64 + i * 16 + l15;
        bfv[i] = *(short8*)(Bs + n * 64 + 8 * (c ^ (n & 7)));
      }
#pragma unroll
      for (int i = 0; i < 4; ++i)
#pragma unroll
        for (int j = 0; j < 4; ++j)
          acc[i][j] = __builtin_amdgcn_mfma_f32_16x16x32_bf16(
              af[i], bfv[j], acc[i][j], 0, 0, 0);
    }
    __syncthreads();
  }

  float bv4[4];
#pragma unroll
  for (int j = 0; j < 4; ++j) {
    int col = wc * 64 + j * 16 + l15;
    bv4[j] = bias ? bias[col0 + col] : 0.f;
  }
#pragma unroll
  for (int i = 0; i < 4; ++i) {
#pragma unroll
    for (int r = 0; r < 4; ++r) {
      int row = mb + wr * 64 + i * 16 + lg * 4 + r;
      if (row < M) {
#pragma unroll
        for (int j = 0; j < 4; ++j) {
          int col = wc * 64 + j * 16 + l15;
          float v = acc[i][j][r] + bv4[j];
          if (OUTBF16)
            ((short*)Cp)[(size_t)row * LDC + col0 + col] = f2bf(v);
          else
            ((float*)Cp)[(size_t)row * LDC + col0 + col] = v;
        }
      }
    }
  }
}

// ---- fused attention v11: 3 centers per wave (attn7 skeleton, NO occupancy
// attributes), X gathers for all 3 centers issued TOGETHER after softmax
// (one shared tail round-trip) instead of early prefetch -- cuts 96 live
// VGPRs out of the MFMA phase so 3 centers fit without spill. Per-center
// arithmetic order unchanged -> bit-identical output.
__global__ __launch_bounds__(256) void k_attn11(
    const short* __restrict__ XY, const float* __restrict__ P,
    const int* __restrict__ nodes, const int* __restrict__ nidx,
    const int* __restrict__ nmask, const short* __restrict__ w2T,
    const float* __restrict__ b2, const float* __restrict__ w3,
    const float* __restrict__ b3, float* __restrict__ out) {
  __shared__ float sc_s[4][3][32];
  __shared__ float att_s[4][3][32];
  const int tid = threadIdx.x;
  const int wave = tid >> 6, lane = tid & 63;
  const int l15 = lane & 15, lg = lane >> 4;
  const int dl = lane & 31;
  const int gw = blockIdx.x * 4 + wave;
  const int b0 = gw * 3, b1 = b0 + 1, b2c = b0 + 2;
  const int c0v = (b0 < BB_), c1v = (b1 < BB_), c2v = (b2c < BB_);
  const int a0 = c0v ? b0 : 0, a1c = c1v ? b1 : 0, a2c = c2v ? b2c : 0;
  const float b3v = b3[0];

  // ---- RT1: indices + masks (3 centers)
  const int ni0 = nidx[a0 * DD + dl];
  const int ni1 = nidx[a1c * DD + dl];
  const int ni2 = nidx[a2c * DD + dl];
  const int m0 = nmask[a0 * DD + dl];
  const int m1 = nmask[a1c * DD + dl];
  const int m2 = nmask[a2c * DD + dl];

  const int r00 = __shfl(ni0, l15), r01 = __shfl(ni0, 16 + l15);
  const int r10 = __shfl(ni1, l15), r11 = __shfl(ni1, 16 + l15);
  const int r20 = __shfl(ni2, l15), r21 = __shfl(ni2, 16 + l15);

  // ---- RT2: Y rows for all 3 centers (max outstanding) + P(c0)
  short8 y00[4], y01[4], y10[4], y11[4], y20[4], y21[4];
#pragma unroll
  for (int ks = 0; ks < 4; ++ks) {
    const int k0 = ks * 32 + lg * 8;
    y00[ks] = *(const short8*)(XY + (size_t)r00 * 256 + 128 + k0);
    y01[ks] = *(const short8*)(XY + (size_t)r01 * 256 + 128 + k0);
    y10[ks] = *(const short8*)(XY + (size_t)r10 * 256 + 128 + k0);
    y11[ks] = *(const short8*)(XY + (size_t)r11 * 256 + 128 + k0);
    y20[ks] = *(const short8*)(XY + (size_t)r20 * 256 + 128 + k0);
    y21[ks] = *(const short8*)(XY + (size_t)r21 * 256 + 128 + k0);
  }
  float4 pv[8];
#pragma unroll
  for (int q = 0; q < 4; ++q) {
    const int k0 = q * 32 + lg * 8;
    pv[2 * q] = *(const float4*)(P + (size_t)a0 * EE + k0);
    pv[2 * q + 1] = *(const float4*)(P + (size_t)a0 * EE + k0 + 4);
  }

  // ---- h1(c0); then P(c1); h1(c1); then P(c2); h1(c2)
  short8 f00[4], f01[4], f10[4], f11[4], f20[4], f21[4];
#pragma unroll
  for (int ks = 0; ks < 4; ++ks) {
    float pf[8] = {pv[2 * ks].x, pv[2 * ks].y, pv[2 * ks].z, pv[2 * ks].w,
                   pv[2 * ks + 1].x, pv[2 * ks + 1].y, pv[2 * ks + 1].z,
                   pv[2 * ks + 1].w};
#pragma unroll
    for (int e = 0; e < 8; ++e) {
      f00[ks][e] = f2bf(fmaxf(bf2f(y00[ks][e]) + pf[e], 0.f));
      f01[ks][e] = f2bf(fmaxf(bf2f(y01[ks][e]) + pf[e], 0.f));
    }
  }
#pragma unroll
  for (int q = 0; q < 4; ++q) {
    const int k0 = q * 32 + lg * 8;
    pv[2 * q] = *(const float4*)(P + (size_t)a1c * EE + k0);
    pv[2 * q + 1] = *(const float4*)(P + (size_t)a1c * EE + k0 + 4);
  }
#pragma unroll
  for (int ks = 0; ks < 4; ++ks) {
    float pf[8] = {pv[2 * ks].x, pv[2 * ks].y, pv[2 * ks].z, pv[2 * ks].w,
                   pv[2 * ks + 1].x, pv[2 * ks + 1].y, pv[2 * ks + 1].z,
                   pv[2 * ks + 1].w};
#pragma unroll
    for (int e = 0; e < 8; ++e) {
      f10[ks][e] = f2bf(fmaxf(bf2f(y10[ks][e]) + pf[e], 0.f));
      f11[ks][e] = f2bf(fmaxf(bf2f(y11[ks][e]) + pf[e], 0.f));
    }
  }
#pragma unroll
  for (int q = 0; q < 4; ++q) {
    const int k0 = q * 32 + lg * 8;
    pv[2 * q] = *(const float4*)(P + (size_t)a2c * EE + k0);
    pv[2 * q + 1] = *(const float4*)(P + (size_t)a2c * EE + k0 + 4);
  }
#pragma unroll
  for (int ks = 0; ks < 4; ++ks) {
    float pf[8] = {pv[2 * ks].x, pv[2 * ks].y, pv[2 * ks].z, pv[2 * ks].w,
                   pv[2 * ks + 1].x, pv[2 * ks + 1].y, pv[2 * ks + 1].z,
                   pv[2 * ks + 1].w};
#pragma unroll
    for (int e = 0; e < 8; ++e) {
      f20[ks][e] = f2bf(fmaxf(bf2f(y20[ks][e]) + pf[e], 0.f));
      f21[ks][e] = f2bf(fmaxf(bf2f(y21[ks][e]) + pf[e], 0.f));
    }
  }

  // ---- MFMA blocks: serialized per center, shared accumulator ----
  float sp0[2][4], sp1[2][4], sp2[2][4];
#pragma unroll
  for (int i = 0; i < 2; ++i)
#pragma unroll
    for (int r = 0; r < 4; ++r) {
      sp0[i][r] = 0.f; sp1[i][r] = 0.f; sp2[i][r] = 0.f;
    }

#pragma unroll
  for (int c = 0; c < 3; ++c) {
#pragma unroll
    for (int cg = 0; cg < 2; ++cg) {
      f32x4 ac[2][4];
#pragma unroll
      for (int i = 0; i < 2; ++i)
#pragma unroll
        for (int j = 0; j < 4; ++j) ac[i][j] = (f32x4){0.f, 0.f, 0.f, 0.f};
#pragma unroll
      for (int ks = 0; ks < 4; ++ks) {
        const int k0 = ks * 32 + lg * 8;
        short8 bfv[4];
#pragma unroll
        for (int j = 0; j < 4; ++j)
          bfv[j] = *(const short8*)(w2T +
              (size_t)(cg * 64 + j * 16 + l15) * EE + k0);
        const short8 fa = (c == 0) ? f00[ks] : (c == 1) ? f10[ks] : f20[ks];
        const short8 fb = (c == 0) ? f01[ks] : (c == 1) ? f11[ks] : f21[ks];
        __builtin_amdgcn_s_setprio(1);
#pragma unroll
        for (int j = 0; j < 4; ++j) {
          ac[0][j] = __builtin_amdgcn_mfma_f32_16x16x32_bf16(
              fa, bfv[j], ac[0][j], 0, 0, 0);
          ac[1][j] = __builtin_amdgcn_mfma_f32_16x16x32_bf16(
              fb, bfv[j], ac[1][j], 0, 0, 0);
        }
        __builtin_amdgcn_s_setprio(0);
      }
#pragma unroll
      for (int j = 0; j < 4; ++j) {
        const int col = cg * 64 + j * 16 + l15;
        const float b2v = b2[col];
        const float w3v = w3[col];
#pragma unroll
        for (int i = 0; i < 2; ++i)
#pragma unroll
          for (int r = 0; r < 4; ++r) {
            const float v = fmaxf(ac[i][j][r] + b2v, 0.f) * w3v;
            if (c == 0) sp0[i][r] += v;
            else if (c == 1) sp1[i][r] += v;
            else sp2[i][r] += v;
          }
      }
    }
  }

  // ---- reduce score partials across the 16-lane col group
#pragma unroll
  for (int off = 1; off <= 8; off <<= 1) {
#pragma unroll
    for (int i = 0; i < 2; ++i)
#pragma unroll
      for (int r = 0; r < 4; ++r) {
        sp0[i][r] += __shfl_xor(sp0[i][r], off);
        sp1[i][r] += __shfl_xor(sp1[i][r], off);
        sp2[i][r] += __shfl_xor(sp2[i][r], off);
      }
  }
  if (l15 == 0) {
#pragma unroll
    for (int i = 0; i < 2; ++i)
#pragma unroll
      for (int r = 0; r < 4; ++r) {
        sc_s[wave][0][i * 16 + lg * 4 + r] = sp0[i][r];
        sc_s[wave][1][i * 16 + lg * 4 + r] = sp1[i][r];
        sc_s[wave][2][i * 16 + lg * 4 + r] = sp2[i][r];
      }
  }

  // ---- softmax: dual (c0 lanes 0-31, c1 lanes 32-63), then c2 full-wave
  const int half = lane >> 5;
  {
    const int mh = half ? m1 : m0;
    float s = sc_s[wave][half][dl] + b3v;
    if (!mh) s = -1e30f;
    float mx = s;
#pragma unroll
    for (int off = 1; off <= 16; off <<= 1)
      mx = fmaxf(mx, __shfl_xor(mx, off));
    float e = expf(s - mx);
    float sum = e;
#pragma unroll
    for (int off = 1; off <= 16; off <<= 1) sum += __shfl_xor(sum, off);
    att_s[wave][half][dl] = e / sum;
  }
  {
    float s = sc_s[wave][2][dl] + b3v;
    if (!m2) s = -1e30f;
    float mx = s;
#pragma unroll
    for (int off = 1; off <= 16; off <<= 1)
      mx = fmaxf(mx, __shfl_xor(mx, off));
    float e = expf(s - mx);
    float sum = e;
#pragma unroll
    for (int off = 1; off <= 16; off <<= 1) sum += __shfl_xor(sum, off);
    if (lane < 32) att_s[wave][2][dl] = e / sum;
  }
  const unsigned long long bal01 = __ballot((half ? m1 : m0) != 0);
  const bool has0 = (bal01 & 0xffffffffull) != 0ull;
  const bool has1 = (bal01 >> 32) != 0ull;
  const bool has2 = (__ballot(m2 != 0) != 0ull);

  // ---- tail: issue ALL X gathers together (3 centers, one round-trip)
  unsigned xv0[32], xv1[32], xv2[32];
#pragma unroll
  for (int d = 0; d < 32; ++d)
    xv0[d] = *(const unsigned*)(XY + (size_t)__shfl(ni0, d) * 256 + 2 * lane);
#pragma unroll
  for (int d = 0; d < 32; ++d)
    xv1[d] = *(const unsigned*)(XY + (size_t)__shfl(ni1, d) * 256 + 2 * lane);
#pragma unroll
  for (int d = 0; d < 32; ++d)
    xv2[d] = *(const unsigned*)(XY + (size_t)__shfl(ni2, d) * 256 + 2 * lane);

  // ---- agg all 3 centers
  if (c0v) {
    float s0 = 0.f, s1 = 0.f;
    if (has0) {
#pragma unroll
      for (int d = 0; d < 32; ++d) {
        const float a = att_s[wave][0][d];
        s0 += a * bf2f((short)(xv0[d] & 0xffffu));
        s1 += a * bf2f((short)(xv0[d] >> 16));
      }
    } else {
      const unsigned xfb =
          *(const unsigned*)(XY + (size_t)nodes[b0] * 256 + 2 * lane);
      s0 = bf2f((short)(xfb & 0xffffu));
      s1 = bf2f((short)(xfb >> 16));
    }
    *(float2*)(out + (size_t)b0 * EE + 2 * lane) = make_float2(s0, s1);
  }
  if (c1v) {
    float s0 = 0.f, s1 = 0.f;
    if (has1) {
#pragma unroll
      for (int d = 0; d < 32; ++d) {
        const float a = att_s[wave][1][d];
        s0 += a * bf2f((short)(xv1[d] & 0xffffu));
        s1 += a * bf2f((short)(xv1[d] >> 16));
      }
    } else {
      const unsigned xfb =
          *(const unsigned*)(XY + (size_t)nodes[b1] * 256 + 2 * lane);
      s0 = bf2f((short)(xfb & 0xffffu));
      s1 = bf2f((short)(xfb >> 16));
    }
    *(float2*)(out + (size_t)b1 * EE + 2 * lane) = make_float2(s0, s1);
  }
  if (c2v) {
    float s0 = 0.f, s1 = 0.f;
    if (has2) {
#pragma unroll
      for (int d = 0; d < 32; ++d) {
        const float a = att_s[wave][2][d];
        s0 += a * bf2f((short)(xv2[d] & 0xffffu));
        s1 += a * bf2f((short)(xv2[d] >> 16));
      }
    } else {
      const unsigned xfb =
          *(const unsigned*)(XY + (size_t)nodes[b2c] * 256 + 2 * lane);
      s0 = bf2f((short)(xfb & 0xffffu));
      s1 = bf2f((short)(xfb >> 16));
    }
    *(float2*)(out + (size_t)b2c * EE + 2 * lane) = make_float2(s0, s1);
  }
}

extern "C" void kernel_launch(void* const* d_in, const int* in_sizes, int n_in,
                              void* d_out, int out_size, void* d_ws,
                              size_t ws_size, hipStream_t stream) {
  const int* nodes = (const int*)d_in[0];
  const int* nidx = (const int*)d_in[1];
  const int* nmask = (const int*)d_in[2];
  const float* feature = (const float*)d_in[3];
  const float* W = (const float*)d_in[4];
  const float* bb = (const float*)d_in[5];
  const float* qz = (const float*)d_in[6];
  const float* a1w = (const float*)d_in[7];
  const float* a1b = (const float*)d_in[8];
  const float* a2w = (const float*)d_in[9];
  const float* a2b = (const float*)d_in[10];
  const float* a3w = (const float*)d_in[11];
  const float* a3b = (const float*)d_in[12];
  float* out = (float*)d_out;

  char* ws = (char*)d_ws;
  short* BT2   = (short*)(ws);                       // 128 KiB [256][256] bf16
  float* Wef32 = (float*)(ws + 131072);              // 128 KiB
  short* a1wTc = (short*)(ws + 262144);              // 32 KiB
  short* w2T   = (short*)(ws + 294912);              // 32 KiB
  float* bias2 = (float*)(ws + 327680);              // 1 KiB
  short* XYb   = (short*)(ws + 524288);              // 51.2 MB bf16 [N][256]
  float* Pv    = (float*)(ws + 524288 + 51200000);   // 5.12 MB fp32

  k_prep<<<257, 256, 0, stream>>>(W, qz, a1w, a2w, bb, Wef32, BT2, a1wTc, w2T,
                                  bias2);
  k_compose<<<128, 256, 0, stream>>>(Wef32, a1w, a1b, bb, BT2, bias2);
  // XY = feature @ [We|Wy] + bias2    [100000,256]x[256,256] -> bf16
  k_xy<<<512, 256, 0, stream>>>(feature, BT2, bias2, XYb, NN);
  // P = X[nodes] @ att1_w[128:]       [10000,128]x[128,128] -> fp32
  k_mm<128, 256, 128, false, false><<<dim3((BB_ + 127) / 128, 1), 256, 0,
                                      stream>>>(XYb, a1wTc, nullptr, nodes, Pv,
                                                BB_);
  // fused attention: 3 centers/wave, tail-batched X gathers (834*12 >= 10000)
  k_attn11<<<834, 256, 0, stream>>>(XYb, Pv, nodes, nidx, nmask, w2T, a2b,
                                    a3w, a3b, out);
}

// Round 17
// 113.394 us; speedup vs baseline: 1.8974x; 1.2829x over previous
//
#include <hip/hip_runtime.h>
#include <hip/hip_bf16.h>
#include <math.h>

#define NN 100000
#define FF 256
#define EE 128
#define BB_ 10000
#define DD 32

typedef __attribute__((ext_vector_type(8))) short short8;
typedef __attribute__((ext_vector_type(4))) float f32x4;

__device__ __forceinline__ short f2bf(float f) {
  __hip_bfloat16 h = __float2bfloat16(f);   // HW RNE cvt
  union { __hip_bfloat16 h; short s; } u; u.h = h;
  return u.s;
}
__device__ __forceinline__ float bf2f(short s) {
  union { unsigned u; float f; } v;
  v.u = ((unsigned)(unsigned short)s) << 16;
  return v.f;
}

// async global->LDS, 16B per lane; LDS dest = wave-uniform base + lane*16
__device__ __forceinline__ void gll16(const float* g, float* lds) {
  __builtin_amdgcn_global_load_lds(
      (const __attribute__((address_space(1))) unsigned int*)g,
      (__attribute__((address_space(3))) unsigned int*)lds, 16, 0, 0);
}

// ---- prep: Wef32 = W*z (fp32), BT2 X-rows, a1wTc, w2T, bias2[0:128] ----
__global__ __launch_bounds__(256) void k_prep(
    const float* __restrict__ W, const float* __restrict__ qz,
    const float* __restrict__ a1w, const float* __restrict__ a2w,
    const float* __restrict__ bb,
    float* __restrict__ Wef32, short* __restrict__ BT2,
    short* __restrict__ a1wTc, short* __restrict__ w2T,
    float* __restrict__ bias2) {
  int i = blockIdx.x * 256 + threadIdx.x;
  if (i < 32768) {                       // (f,e): We = W*z
    int f = i >> 7, e = i & 127;
    float g = qz[f];
    float s = 1.0f / (1.0f + expf(-g));
    float z = fminf(fmaxf(s * 1.2f - 0.1f, 0.0f), 1.0f);
    float v = W[f * 128 + e] * z;
    Wef32[f * 128 + e] = v;
    BT2[e * 256 + f] = f2bf(v);          // X-part rows of combined BT
  } else if (i < 49152) {                // a1wTc[n][k] = a1w[128+k][n]
    int t = i - 32768; int n = t >> 7, k = t & 127;
    a1wTc[n * 128 + k] = f2bf(a1w[(128 + k) * 128 + n]);
  } else if (i < 65536) {                // w2T[n][k] = a2w[k][n]
    int t = i - 49152; int n = t >> 7, k = t & 127;
    w2T[n * 128 + k] = f2bf(a2w[k * 128 + n]);
  } else if (i < 65664) {                // bias2[0:128] = b
    bias2[i - 65536] = bb[i - 65536];
  }
}

// ---- compose: BT2 Y-rows = (We @ A1n)^T, bias2[128:] = b@A1n + a1b ----
__global__ __launch_bounds__(256) void k_compose(
    const float* __restrict__ Wef32, const float* __restrict__ a1w,
    const float* __restrict__ a1b, const float* __restrict__ bb,
    short* __restrict__ BT2, float* __restrict__ bias2) {
  const int n = blockIdx.x;       // 0..127 output col of Y
  const int f = threadIdx.x;      // 0..255
  float s = 0.f;
  for (int e = 0; e < 128; ++e)
    s = fmaf(a1w[e * 128 + n], Wef32[f * 128 + e], s);
  BT2[(size_t)(128 + n) * 256 + f] = f2bf(s);
  if (f == 0) {
    float by = a1b[n];
    for (int e = 0; e < 128; ++e) by = fmaf(bb[e], a1w[e * 128 + n], by);
    bias2[128 + n] = by;
  }
}

// ---- XY GEMM v6: persistent blocks, double-buffered gll staging, counted
// vmcnt.  XY[M][256] = feature[M][256] @ BT2[256][256]^T + bias2
__global__ __launch_bounds__(256) void k_xy(
    const float* __restrict__ feat, const short* __restrict__ BT2,
    const float* __restrict__ bias2, short* __restrict__ XY, int M) {
  __shared__ float As[2][32 * 256];   // 2 x 32 KiB fp32
  const int tid = threadIdx.x;
  const int wave = tid >> 6, lane = tid & 63;
  const int wn = wave;                        // col block
  const int l15 = lane & 15, lg = lane >> 4;
  const int NT = M >> 5;                      // 3125 (M % 32 == 0)
  const int G = gridDim.x;

  // ---- B fragments + bias: hoisted, one L2 round-trip
  short8 bfr[8][4];
#pragma unroll
  for (int ks = 0; ks < 8; ++ks)
#pragma unroll
    for (int j = 0; j < 4; ++j)
      bfr[ks][j] = *(const short8*)(BT2 +
          (size_t)(wn * 64 + j * 16 + l15) * 256 + (ks * 4 + lg) * 8);
  float bv4[4];
#pragma unroll
  for (int j = 0; j < 4; ++j) bv4[j] = bias2[wn * 64 + j * 16 + l15];

  int t = blockIdx.x;
  if (t < NT) {                               // prologue: stage tile t -> buf0
#pragma unroll
    for (int it = 0; it < 8; ++it) {
      int r = it * 4 + wave;
      gll16(feat + (size_t)(t * 32 + r) * 256 + ((lane ^ (r & 7)) * 4),
            &As[0][r * 256]);
    }
  }

  int cur = 0;
  for (; t < NT; t += G) {
    const int tn = t + G;
    __builtin_amdgcn_s_barrier();             // b1: buf (cur^1) free to fill
    if (tn < NT) {
#pragma unroll
      for (int it = 0; it < 8; ++it) {
        int r = it * 4 + wave;
        gll16(feat + (size_t)(tn * 32 + r) * 256 + ((lane ^ (r & 7)) * 4),
              &As[cur ^ 1][r * 256]);
      }
      asm volatile("s_waitcnt vmcnt(8)" ::: "memory");  // cur landed; 8 fly on
    } else {
      asm volatile("s_waitcnt vmcnt(0)" ::: "memory");  // tail: drain all
    }
    __builtin_amdgcn_s_barrier();             // b2: cur visible to all waves
    __builtin_amdgcn_sched_barrier(0);

    f32x4 acc[2][4];
#pragma unroll
    for (int i = 0; i < 2; ++i)
#pragma unroll
      for (int j = 0; j < 4; ++j) acc[i][j] = (f32x4){0.f, 0.f, 0.f, 0.f};

    const float* Ab = &As[cur][0];
#pragma unroll
    for (int ks = 0; ks < 8; ++ks) {
      const int kg = ks * 4 + lg;             // 8-float k-group
#pragma unroll
      for (int i = 0; i < 2; ++i) {
        const int r = i * 16 + l15;
        const int sw = r & 7;
        const int c0 = (2 * kg) ^ sw;
        const int c1 = (2 * kg + 1) ^ sw;
        float4 flo = *(const float4*)(Ab + r * 256 + c0 * 4);
        float4 fhi = *(const float4*)(Ab + r * 256 + c1 * 4);
        short8 af;
        af[0] = f2bf(flo.x); af[1] = f2bf(flo.y);
        af[2] = f2bf(flo.z); af[3] = f2bf(flo.w);
        af[4] = f2bf(fhi.x); af[5] = f2bf(fhi.y);
        af[6] = f2bf(fhi.z); af[7] = f2bf(fhi.w);
        __builtin_amdgcn_s_setprio(1);
#pragma unroll
        for (int j = 0; j < 4; ++j)
          acc[i][j] = __builtin_amdgcn_mfma_f32_16x16x32_bf16(
              af, bfr[ks][j], acc[i][j], 0, 0, 0);
        __builtin_amdgcn_s_setprio(0);
      }
    }

#pragma unroll
    for (int i = 0; i < 2; ++i) {
#pragma unroll
      for (int r = 0; r < 4; ++r) {
        int row = t * 32 + i * 16 + lg * 4 + r;
#pragma unroll
        for (int j = 0; j < 4; ++j) {
          int col = wn * 64 + j * 16 + l15;
          XY[(size_t)row * 256 + col] = f2bf(acc[i][j][r] + bv4[j]);
        }
      }
    }
    cur ^= 1;
  }
}

// ---- MFMA GEMM (used for P): C = A(rows via idx, stride LDA)@BT^T + bias --
template <int K, int LDA, int LDC, bool AF32, bool OUTBF16>
__global__ __launch_bounds__(256) void k_mm(
    const void* __restrict__ Ap, const short* __restrict__ BT,
    const float* __restrict__ bias, const int* __restrict__ idx,
    void* __restrict__ Cp, int M) {
  __shared__ short As[128 * 64];
  __shared__ short Bs[128 * 64];
  const int tid = threadIdx.x;
  const int mb = blockIdx.x * 128;
  const int col0 = blockIdx.y * 128;
  const int wave = tid >> 6, lane = tid & 63;
  const int wr = wave >> 1, wc = wave & 1;
  const int l15 = lane & 15, lg = lane >> 4;

  size_t abase[4];
#pragma unroll
  for (int s = 0; s < 4; ++s) {
    int row = (tid + s * 256) >> 3;
    int grow = mb + row;
    int gr = 0;
    if (grow < M) gr = idx ? idx[grow] : grow;
    abase[s] = (size_t)gr * LDA;
  }

  f32x4 acc[4][4];
#pragma unroll
  for (int i = 0; i < 4; ++i)
#pragma unroll
    for (int j = 0; j < 4; ++j) acc[i][j] = (f32x4){0.f, 0.f, 0.f, 0.f};

  for (int k0 = 0; k0 < K; k0 += 64) {
#pragma unroll
    for (int s = 0; s < 4; ++s) {
      int q = tid + s * 256;
      int row = q >> 3, c = q & 7;
      short8 av;
      if (AF32) {
        const float* ap = (const float*)Ap + abase[s] + k0 + c * 8;
        float4 f0 = *(const float4*)ap;
        float4 f1 = *(const float4*)(ap + 4);
        av[0] = f2bf(f0.x); av[1] = f2bf(f0.y);
        av[2] = f2bf(f0.z); av[3] = f2bf(f0.w);
        av[4] = f2bf(f1.x); av[5] = f2bf(f1.y);
        av[6] = f2bf(f1.z); av[7] = f2bf(f1.w);
      } else {
        av = *(const short8*)((const short*)Ap + abase[s] + k0 + c * 8);
      }
      *(short8*)(As + row * 64 + 8 * (c ^ (row & 7))) = av;
      short8 bv = *(const short8*)(BT + (size_t)(col0 + row) * K + k0 + c * 8);
      *(short8*)(Bs + row * 64 + 8 * (c ^ (row & 7))) = bv;
    }
    __syncthreads();
#pragma unroll
    for (int ks = 0; ks < 2; ++ks) {
      int c = ks * 4 + lg;
      short8 af[4], bfv[4];
#pragma unroll
      for (int i = 0; i < 4; ++i) {
        int r = wr * 64 + i * 16 + l15;
        af[i] = *(short8*)(As + r * 64 + 8 * (c ^ (r & 7)));
        int n = wc * 64 + i * 16 + l15;
        bfv[i] = *(short8*)(Bs + n * 64 + 8 * (c ^ (n & 7)));
      }
#pragma unroll
      for (int i = 0; i < 4; ++i)
#pragma unroll
        for (int j = 0; j < 4; ++j)
          acc[i][j] = __builtin_amdgcn_mfma_f32_16x16x32_bf16(
              af[i], bfv[j], acc[i][j], 0, 0, 0);
    }
    __syncthreads();
  }

  float bv4[4];
#pragma unroll
  for (int j = 0; j < 4; ++j) {
    int col = wc * 64 + j * 16 + l15;
    bv4[j] = bias ? bias[col0 + col] : 0.f;
  }
#pragma unroll
  for (int i = 0; i < 4; ++i) {
#pragma unroll
    for (int r = 0; r < 4; ++r) {
      int row = mb + wr * 64 + i * 16 + lg * 4 + r;
      if (row < M) {
#pragma unroll
        for (int j = 0; j < 4; ++j) {
          int col = wc * 64 + j * 16 + l15;
          float v = acc[i][j][r] + bv4[j];
          if (OUTBF16)
            ((short*)Cp)[(size_t)row * LDC + col0 + col] = f2bf(v);
          else
            ((float*)Cp)[(size_t)row * LDC + col0 + col] = v;
        }
      }
    }
  }
}

// ---- fused attention v7: 2 centers per wave, phase-interleaved.
// Doubles per-wave loads in flight; w2T B-fragments shared by both centers'
// MFMAs; dual softmax (lanes 0-31 = c0, 32-63 = c1). Same arithmetic order
// per center as attn4/5/6 -> bit-identical output.  [Session best: 60.7 us]
__global__ __launch_bounds__(256) void k_attn7(
    const short* __restrict__ XY, const float* __restrict__ P,
    const int* __restrict__ nodes, const int* __restrict__ nidx,
    const int* __restrict__ nmask, const short* __restrict__ w2T,
    const float* __restrict__ b2, const float* __restrict__ w3,
    const float* __restrict__ b3, float* __restrict__ out) {
  __shared__ float sc_s[4][2][32];
  __shared__ float att_s[4][2][32];
  const int tid = threadIdx.x;
  const int wave = tid >> 6, lane = tid & 63;
  const int l15 = lane & 15, lg = lane >> 4;
  const int dl = lane & 31;
  const int b0 = (blockIdx.x * 4 + wave) * 2;
  const int b1 = b0 + 1;
  const float b3v = b3[0];

  // hoisted fold coefficients
  float b2h[2][4], w3h[2][4];
#pragma unroll
  for (int cg = 0; cg < 2; ++cg)
#pragma unroll
    for (int j = 0; j < 4; ++j) {
      const int col = cg * 64 + j * 16 + l15;
      b2h[cg][j] = b2[col];
      w3h[cg][j] = w3[col];
    }

  // ---- RT1: indices, masks, fallback rows (both centers)
  const int ni0 = nidx[b0 * DD + dl];
  const int ni1 = nidx[b1 * DD + dl];
  const int m0 = nmask[b0 * DD + dl];
  const int m1 = nmask[b1 * DD + dl];
  const unsigned xfb0 =
      *(const unsigned*)(XY + (size_t)nodes[b0] * 256 + 2 * lane);
  const unsigned xfb1 =
      *(const unsigned*)(XY + (size_t)nodes[b1] * 256 + 2 * lane);

  const int r00 = __shfl(ni0, l15), r01 = __shfl(ni0, 16 + l15);
  const int r10 = __shfl(ni1, l15), r11 = __shfl(ni1, 16 + l15);

  // ---- RT2: Y rows for both centers + P(c0)
  short8 y00[4], y01[4], y10[4], y11[4];
#pragma unroll
  for (int ks = 0; ks < 4; ++ks) {
    const int k0 = ks * 32 + lg * 8;
    y00[ks] = *(const short8*)(XY + (size_t)r00 * 256 + 128 + k0);
    y01[ks] = *(const short8*)(XY + (size_t)r01 * 256 + 128 + k0);
    y10[ks] = *(const short8*)(XY + (size_t)r10 * 256 + 128 + k0);
    y11[ks] = *(const short8*)(XY + (size_t)r11 * 256 + 128 + k0);
  }
  float4 pv[8];
#pragma unroll
  for (int q = 0; q < 4; ++q) {
    const int k0 = q * 32 + lg * 8;
    pv[2 * q] = *(const float4*)(P + (size_t)b0 * EE + k0);
    pv[2 * q + 1] = *(const float4*)(P + (size_t)b0 * EE + k0 + 4);
  }

  // ---- h1(c0) -> fragments (frees y00/y01 and pv)
  short8 f00[4], f01[4];
#pragma unroll
  for (int ks = 0; ks < 4; ++ks) {
    float pf[8] = {pv[2 * ks].x, pv[2 * ks].y, pv[2 * ks].z, pv[2 * ks].w,
                   pv[2 * ks + 1].x, pv[2 * ks + 1].y, pv[2 * ks + 1].z,
                   pv[2 * ks + 1].w};
#pragma unroll
    for (int e = 0; e < 8; ++e) {
      f00[ks][e] = f2bf(fmaxf(bf2f(y00[ks][e]) + pf[e], 0.f));
      f01[ks][e] = f2bf(fmaxf(bf2f(y01[ks][e]) + pf[e], 0.f));
    }
  }

  // ---- issue P(c1) + X gathers (c0)
#pragma unroll
  for (int q = 0; q < 4; ++q) {
    const int k0 = q * 32 + lg * 8;
    pv[2 * q] = *(const float4*)(P + (size_t)b1 * EE + k0);
    pv[2 * q + 1] = *(const float4*)(P + (size_t)b1 * EE + k0 + 4);
  }
  unsigned xv0[32];
#pragma unroll
  for (int d = 0; d < 32; ++d)
    xv0[d] = *(const unsigned*)(XY + (size_t)__shfl(ni0, d) * 256 + 2 * lane);

  // ---- h1(c1) -> fragments
  short8 f10[4], f11[4];
#pragma unroll
  for (int ks = 0; ks < 4; ++ks) {
    float pf[8] = {pv[2 * ks].x, pv[2 * ks].y, pv[2 * ks].z, pv[2 * ks].w,
                   pv[2 * ks + 1].x, pv[2 * ks + 1].y, pv[2 * ks + 1].z,
                   pv[2 * ks + 1].w};
#pragma unroll
    for (int e = 0; e < 8; ++e) {
      f10[ks][e] = f2bf(fmaxf(bf2f(y10[ks][e]) + pf[e], 0.f));
      f11[ks][e] = f2bf(fmaxf(bf2f(y11[ks][e]) + pf[e], 0.f));
    }
  }

  // ---- col-split att2 MFMA, B-fragments shared by both centers
  float sp0[2][4], sp1[2][4];
#pragma unroll
  for (int i = 0; i < 2; ++i)
#pragma unroll
    for (int r = 0; r < 4; ++r) { sp0[i][r] = 0.f; sp1[i][r] = 0.f; }

#pragma unroll
  for (int cg = 0; cg < 2; ++cg) {
    f32x4 ac0[2][4], ac1[2][4];
#pragma unroll
    for (int i = 0; i < 2; ++i)
#pragma unroll
      for (int j = 0; j < 4; ++j) {
        ac0[i][j] = (f32x4){0.f, 0.f, 0.f, 0.f};
        ac1[i][j] = (f32x4){0.f, 0.f, 0.f, 0.f};
      }
#pragma unroll
    for (int ks = 0; ks < 4; ++ks) {
      const int k0 = ks * 32 + lg * 8;
      short8 bfv[4];
#pragma unroll
      for (int j = 0; j < 4; ++j)
        bfv[j] = *(const short8*)(w2T +
            (size_t)(cg * 64 + j * 16 + l15) * EE + k0);
      __builtin_amdgcn_s_setprio(1);
#pragma unroll
      for (int j = 0; j < 4; ++j) {
        ac0[0][j] = __builtin_amdgcn_mfma_f32_16x16x32_bf16(
            f00[ks], bfv[j], ac0[0][j], 0, 0, 0);
        ac0[1][j] = __builtin_amdgcn_mfma_f32_16x16x32_bf16(
            f01[ks], bfv[j], ac0[1][j], 0, 0, 0);
        ac1[0][j] = __builtin_amdgcn_mfma_f32_16x16x32_bf16(
            f10[ks], bfv[j], ac1[0][j], 0, 0, 0);
        ac1[1][j] = __builtin_amdgcn_mfma_f32_16x16x32_bf16(
            f11[ks], bfv[j], ac1[1][j], 0, 0, 0);
      }
      __builtin_amdgcn_s_setprio(0);
    }
#pragma unroll
    for (int j = 0; j < 4; ++j) {
#pragma unroll
      for (int i = 0; i < 2; ++i)
#pragma unroll
        for (int r = 0; r < 4; ++r) {
          sp0[i][r] += fmaxf(ac0[i][j][r] + b2h[cg][j], 0.f) * w3h[cg][j];
          sp1[i][r] += fmaxf(ac1[i][j][r] + b2h[cg][j], 0.f) * w3h[cg][j];
        }
    }
  }

  // ---- issue X gathers (c1) — consumed at agg(c1)
  unsigned xv1[32];
#pragma unroll
  for (int d = 0; d < 32; ++d)
    xv1[d] = *(const unsigned*)(XY + (size_t)__shfl(ni1, d) * 256 + 2 * lane);

  // ---- reduce score partials across the 16-lane col group
#pragma unroll
  for (int off = 1; off <= 8; off <<= 1) {
#pragma unroll
    for (int i = 0; i < 2; ++i)
#pragma unroll
      for (int r = 0; r < 4; ++r) {
        sp0[i][r] += __shfl_xor(sp0[i][r], off);
        sp1[i][r] += __shfl_xor(sp1[i][r], off);
      }
  }
  if (l15 == 0) {
#pragma unroll
    for (int i = 0; i < 2; ++i)
#pragma unroll
      for (int r = 0; r < 4; ++r) {
        sc_s[wave][0][i * 16 + lg * 4 + r] = sp0[i][r];
        sc_s[wave][1][i * 16 + lg * 4 + r] = sp1[i][r];
      }
  }

  // ---- dual softmax: lanes 0-31 handle c0, lanes 32-63 handle c1
  const int half = lane >> 5;
  const int row = dl;
  const int mh = half ? m1 : m0;
  float s = sc_s[wave][half][row] + b3v;
  if (!mh) s = -1e30f;
  float mx = s;
#pragma unroll
  for (int off = 1; off <= 16; off <<= 1) mx = fmaxf(mx, __shfl_xor(mx, off));
  float e = expf(s - mx);
  float sum = e;
#pragma unroll
  for (int off = 1; off <= 16; off <<= 1) sum += __shfl_xor(sum, off);
  att_s[wave][half][row] = e / sum;
  const unsigned long long bal = __ballot(mh != 0);
  const bool has0 = (bal & 0xffffffffull) != 0ull;
  const bool has1 = (bal >> 32) != 0ull;

  // ---- agg both centers on prefetched X
  float a00 = 0.f, a01 = 0.f;
  if (has0) {
#pragma unroll
    for (int d = 0; d < 32; ++d) {
      const float a = att_s[wave][0][d];
      a00 += a * bf2f((short)(xv0[d] & 0xffffu));
      a01 += a * bf2f((short)(xv0[d] >> 16));
    }
  } else {
    a00 = bf2f((short)(xfb0 & 0xffffu));
    a01 = bf2f((short)(xfb0 >> 16));
  }
  *(float2*)(out + (size_t)b0 * EE + 2 * lane) = make_float2(a00, a01);

  float a10 = 0.f, a11 = 0.f;
  if (has1) {
#pragma unroll
    for (int d = 0; d < 32; ++d) {
      const float a = att_s[wave][1][d];
      a10 += a * bf2f((short)(xv1[d] & 0xffffu));
      a11 += a * bf2f((short)(xv1[d] >> 16));
    }
  } else {
    a10 = bf2f((short)(xfb1 & 0xffffu));
    a11 = bf2f((short)(xfb1 >> 16));
  }
  *(float2*)(out + (size_t)b1 * EE + 2 * lane) = make_float2(a10, a11);
}

extern "C" void kernel_launch(void* const* d_in, const int* in_sizes, int n_in,
                              void* d_out, int out_size, void* d_ws,
                              size_t ws_size, hipStream_t stream) {
  const int* nodes = (const int*)d_in[0];
  const int* nidx = (const int*)d_in[1];
  const int* nmask = (const int*)d_in[2];
  const float* feature = (const float*)d_in[3];
  const float* W = (const float*)d_in[4];
  const float* bb = (const float*)d_in[5];
  const float* qz = (const float*)d_in[6];
  const float* a1w = (const float*)d_in[7];
  const float* a1b = (const float*)d_in[8];
  const float* a2w = (const float*)d_in[9];
  const float* a2b = (const float*)d_in[10];
  const float* a3w = (const float*)d_in[11];
  const float* a3b = (const float*)d_in[12];
  float* out = (float*)d_out;

  char* ws = (char*)d_ws;
  short* BT2   = (short*)(ws);                       // 128 KiB [256][256] bf16
  float* Wef32 = (float*)(ws + 131072);              // 128 KiB
  short* a1wTc = (short*)(ws + 262144);              // 32 KiB
  short* w2T   = (short*)(ws + 294912);              // 32 KiB
  float* bias2 = (float*)(ws + 327680);              // 1 KiB
  short* XYb   = (short*)(ws + 524288);              // 51.2 MB bf16 [N][256]
  float* Pv    = (float*)(ws + 524288 + 51200000);   // 5.12 MB fp32

  k_prep<<<257, 256, 0, stream>>>(W, qz, a1w, a2w, bb, Wef32, BT2, a1wTc, w2T,
                                  bias2);
  k_compose<<<128, 256, 0, stream>>>(Wef32, a1w, a1b, bb, BT2, bias2);
  // XY = feature @ [We|Wy] + bias2    [100000,256]x[256,256] -> bf16
  k_xy<<<512, 256, 0, stream>>>(feature, BT2, bias2, XYb, NN);
  // P = X[nodes] @ att1_w[128:]       [10000,128]x[128,128] -> fp32
  k_mm<128, 256, 128, false, false><<<dim3((BB_ + 127) / 128, 1), 256, 0,
                                      stream>>>(XYb, a1wTc, nullptr, nodes, Pv,
                                                BB_);
  // fused attention + aggregation: 2 centers per wave, phase-interleaved
  k_attn7<<<BB_ / 8, 256, 0, stream>>>(XYb, Pv, nodes, nidx, nmask, w2T, a2b,
                                       a3w, a3b, out);
}